// Round 3
// baseline (773.245 us; speedup 1.0000x reference)
//
#include <hip/hip_runtime.h>
#include <hip/hip_bf16.h>

#define BATCH 32768
#define HD 64
#define ED 16
#define NM 6
#define PP 12
#define TT 30

// ws layout (fp32 words):
//     0 : WT[80][256]   WT[k][gj] = k<16 ? W_ih[gj][k] : W_hh[gj][k-16]
// 20480 : biasG[256]    b_ih + b_hh
// 20736 : Wpos[12][64]
// 21504 : bpos[12]
// 21516 : Wse[16][12]
// 21708 : bse[16]
// 21724 : Wconf[6][64]
// 22108 : bconf[6]
// 22114 : Sx[16]        sum_m W_se[e][2m]
// 22130 : Sy[16]        sum_m W_se[e][2m+1]
// 22528 : dtype flag (int): 1 => inputs are fp32, 0 => inputs are bf16
#define FLAG_IDX 22528

// Detect input dtype: scan W_hh's first 16384 ushorts (32 KB — in-bounds for
// both dtypes). fp32 data read as ushorts contains bf16-NaN patterns in the
// random low half-words (~32 expected); real bf16 weight data never does.
__global__ void detect_kernel(const unsigned short* __restrict__ raw,
                              int* __restrict__ flag_out) {
    __shared__ int sflag[256];
    int local = 0;
    for (int i = threadIdx.x; i < 16384; i += 256) {
        unsigned short u = raw[i];
        if ((u & 0x7F80u) == 0x7F80u) local = 1;
    }
    sflag[threadIdx.x] = local;
    __syncthreads();
    if (threadIdx.x == 0) {
        int f = 0;
        for (int i = 0; i < 256; ++i) f |= sflag[i];
        flag_out[0] = f;
    }
}

__device__ __forceinline__ float ldin(const void* p, int i, int isf32) {
    return isf32 ? ((const float*)p)[i]
                 : (float)((const __hip_bfloat16*)p)[i];
}

__global__ void prep_kernel(const void* __restrict__ W_ih,
                            const void* __restrict__ W_hh,
                            const void* __restrict__ b_ih,
                            const void* __restrict__ b_hh,
                            const void* __restrict__ W_se,
                            const void* __restrict__ b_se,
                            const void* __restrict__ W_pos,
                            const void* __restrict__ b_pos,
                            const void* __restrict__ W_conf,
                            const void* __restrict__ b_conf,
                            float* __restrict__ ws)
{
    const int isf32 = ((const int*)(ws + FLAG_IDX))[0];
    int tid = blockIdx.x * blockDim.x + threadIdx.x;
    int stride = gridDim.x * blockDim.x;
    for (int idx = tid; idx < 80 * 256; idx += stride) {
        int k = idx >> 8, gj = idx & 255;
        ws[idx] = (k < 16) ? ldin(W_ih, gj * 16 + k, isf32)
                           : ldin(W_hh, gj * 64 + (k - 16), isf32);
    }
    for (int idx = tid; idx < 256; idx += stride)
        ws[20480 + idx] = ldin(b_ih, idx, isf32) + ldin(b_hh, idx, isf32);
    for (int idx = tid; idx < 768; idx += stride)
        ws[20736 + idx] = ldin(W_pos, idx, isf32);
    for (int idx = tid; idx < 12; idx += stride)
        ws[21504 + idx] = ldin(b_pos, idx, isf32);
    for (int idx = tid; idx < 192; idx += stride)
        ws[21516 + idx] = ldin(W_se, idx, isf32);
    for (int idx = tid; idx < 16; idx += stride)
        ws[21708 + idx] = ldin(b_se, idx, isf32);
    for (int idx = tid; idx < 384; idx += stride)
        ws[21724 + idx] = ldin(W_conf, idx, isf32);
    for (int idx = tid; idx < 6; idx += stride)
        ws[22108 + idx] = ldin(b_conf, idx, isf32);
    for (int idx = tid; idx < 16; idx += stride) {
        float sx = 0.f, sy = 0.f;
        for (int m = 0; m < 6; ++m) {
            sx += ldin(W_se, idx * 12 + 2 * m, isf32);
            sy += ldin(W_se, idx * 12 + 2 * m + 1, isf32);
        }
        ws[22114 + idx] = sx;
        ws[22130 + idx] = sy;
    }
}

__device__ __forceinline__ float sigmoidf_(float x) {
    return 1.0f / (1.0f + __expf(-x));
}
__device__ __forceinline__ float tanhf_(float x) {
    float ax = fabsf(x);
    float z = __expf(-2.0f * ax);
    float t = (1.0f - z) / (1.0f + z);
    return copysignf(t, x);
}

// block = 512 threads = 8 waves; block owns 64 agents (lane = agent),
// wave w owns hidden units [8w, 8w+8). z = [x(16); h(64)] in LDS transposed.
__global__ __launch_bounds__(512, 4) void lstm_kernel(
    const void* __restrict__ traj_rel,
    const void* __restrict__ h0,
    const void* __restrict__ c0,
    const float* __restrict__ ws,
    float* __restrict__ out)
{
    __shared__ float zT[80 * 64];    // zT[k][a]
    __shared__ float relT[12 * 64];  // relT[p][a]

    const int lane = threadIdx.x & 63;
    const int w = threadIdx.x >> 6;  // 0..7
    const int jbase = __builtin_amdgcn_readfirstlane(w * 8);  // wave-uniform
    const int b = blockIdx.x * 64 + lane;
    const int isf32 = ((const int*)(ws + FLAG_IDX))[0];

    const float* __restrict__ WT    = ws;
    const float* __restrict__ biasG = ws + 20480;
    const float* __restrict__ Wpos  = ws + 20736;
    const float* __restrict__ bpos  = ws + 21504;
    const float* __restrict__ Wse   = ws + 21516;
    const float* __restrict__ bse   = ws + 21708;
    const float* __restrict__ Wconf = ws + 21724;
    const float* __restrict__ bconf = ws + 22108;
    const float* __restrict__ Sx    = ws + 22114;
    const float* __restrict__ Sy    = ws + 22130;

    // ---- init: c in regs, h0 -> LDS, x0 -> LDS ----
    float c[8];
#pragma unroll
    for (int u = 0; u < 8; ++u) c[u] = ldin(c0, b * 64 + jbase + u, isf32);
#pragma unroll
    for (int u = 0; u < 8; ++u)
        zT[(16 + jbase + u) * 64 + lane] = ldin(h0, b * 64 + jbase + u, isf32);
    if (w == 0) {
        float rx = ldin(traj_rel, 2 * b, isf32);
        float ry = ldin(traj_rel, 2 * b + 1, isf32);
#pragma unroll
        for (int e = 0; e < 16; ++e) {
            float x = fmaf(rx, Sx[e], fmaf(ry, Sy[e], bse[e]));
            zT[e * 64 + lane] = x > 0.f ? x : 0.01f * x;
        }
    }
    __syncthreads();

    float2* outp = (float2*)out;  // pred, (x,y) pairs

    for (int t = 0; t < TT; ++t) {
        // ---- phase A: gates = z @ Wcat^T + bias ----
        float acc[4][8];
#pragma unroll
        for (int g = 0; g < 4; ++g)
#pragma unroll
            for (int u = 0; u < 8; ++u)
                acc[g][u] = biasG[g * 64 + jbase + u];
        for (int k = 0; k < 80; ++k) {
            float zk = zT[k * 64 + lane];
            const float* wk = WT + k * 256 + jbase;  // uniform
#pragma unroll
            for (int g = 0; g < 4; ++g)
#pragma unroll
                for (int u = 0; u < 8; ++u)
                    acc[g][u] = fmaf(zk, wk[g * 64 + u], acc[g][u]);
        }
        __syncthreads();

        // ---- phase B: activations, write h_new ----
#pragma unroll
        for (int u = 0; u < 8; ++u) {
            float cn = sigmoidf_(acc[1][u]) * c[u] +
                       sigmoidf_(acc[0][u]) * tanhf_(acc[2][u]);
            float hn = sigmoidf_(acc[3][u]) * tanhf_(cn);
            c[u] = cn;
            zT[(16 + jbase + u) * 64 + lane] = hn;
        }
        __syncthreads();

        // ---- phase C: rel = h @ Wpos^T + bpos (waves 0..5, 2 p's each) ----
        if (w < 6) {
            const int p0 = 2 * w;
            float r0 = bpos[p0], r1 = bpos[p0 + 1];
            const float* wp0 = Wpos + p0 * 64;
            const float* wp1 = wp0 + 64;
            for (int j = 0; j < 64; ++j) {
                float hj = zT[(16 + j) * 64 + lane];
                r0 = fmaf(hj, wp0[j], r0);
                r1 = fmaf(hj, wp1[j], r1);
            }
            relT[p0 * 64 + lane] = r0;
            relT[(p0 + 1) * 64 + lane] = r1;
            float2 v;
            v.x = r0;
            v.y = r1;
            outp[(b * 6 + w) * 30 + t] = v;  // pred[b][m=w][t][0:2]
        }
        __syncthreads();

        // ---- phase D: x = lrelu(rel @ Wse^T + bse) (2 e's per wave) ----
        {
            float r[12];
#pragma unroll
            for (int p = 0; p < 12; ++p) r[p] = relT[p * 64 + lane];
#pragma unroll
            for (int ee = 0; ee < 2; ++ee) {
                int e = 2 * w + ee;
                float x = bse[e];
                const float* wse = Wse + e * 12;
#pragma unroll
                for (int p = 0; p < 12; ++p) x = fmaf(r[p], wse[p], x);
                x = x > 0.f ? x : 0.01f * x;
                zT[e * 64 + lane] = x;
            }
        }
        __syncthreads();
    }

    // ---- conf = softmax(h @ Wconf^T + bconf) (wave 0) ----
    if (w == 0) {
        float l[6];
#pragma unroll
        for (int m = 0; m < 6; ++m) l[m] = bconf[m];
        for (int j = 0; j < 64; ++j) {
            float hj = zT[(16 + j) * 64 + lane];
#pragma unroll
            for (int m = 0; m < 6; ++m) l[m] = fmaf(hj, Wconf[m * 64 + j], l[m]);
        }
        float mx = l[0];
#pragma unroll
        for (int m = 1; m < 6; ++m) mx = fmaxf(mx, l[m]);
        float ex[6], s = 0.f;
#pragma unroll
        for (int m = 0; m < 6; ++m) { ex[m] = __expf(l[m] - mx); s += ex[m]; }
        float inv = 1.0f / s;
        float* confp = out + (size_t)BATCH * 6 * 30 * 2 + (size_t)b * 6;
#pragma unroll
        for (int m = 0; m < 6; ++m) confp[m] = ex[m] * inv;
    }
}

extern "C" void kernel_launch(void* const* d_in, const int* in_sizes, int n_in,
                              void* d_out, int out_size, void* d_ws, size_t ws_size,
                              hipStream_t stream) {
    // inputs: 0 traj_abs (unused), 1 traj_rel, 2 h0, 3 c0, 4 W_ih, 5 W_hh,
    //         6 b_ih, 7 b_hh, 8 W_se, 9 b_se, 10 W_pos, 11 b_pos, 12 W_conf, 13 b_conf
    const void* traj_rel = d_in[1];
    const void* h0   = d_in[2];
    const void* c0   = d_in[3];
    const void* W_ih = d_in[4];
    const void* W_hh = d_in[5];
    const void* b_ih = d_in[6];
    const void* b_hh = d_in[7];
    const void* W_se = d_in[8];
    const void* b_se = d_in[9];
    const void* W_pos  = d_in[10];
    const void* b_pos  = d_in[11];
    const void* W_conf = d_in[12];
    const void* b_conf = d_in[13];
    float* ws = (float*)d_ws;
    float* out = (float*)d_out;

    detect_kernel<<<1, 256, 0, stream>>>((const unsigned short*)W_hh,
                                         (int*)(ws + FLAG_IDX));
    prep_kernel<<<32, 256, 0, stream>>>(W_ih, W_hh, b_ih, b_hh, W_se, b_se,
                                        W_pos, b_pos, W_conf, b_conf, ws);
    lstm_kernel<<<BATCH / 64, 512, 0, stream>>>(traj_rel, h0, c0, ws, out);
}

// Round 4
// 451.974 us; speedup vs baseline: 1.7108x; 1.7108x over previous
//
#include <hip/hip_runtime.h>
#include <hip/hip_bf16.h>

typedef _Float16 half8 __attribute__((ext_vector_type(8)));
typedef float floatx16 __attribute__((ext_vector_type(16)));
typedef float float4v __attribute__((ext_vector_type(4)));

#define BATCH 32768
#define TT 30

// ws offsets (in floats)
#define WFRAG_OFF 0        // f16[8 tiles][5 ks][64 lane][8] = 20480 halves = 10240 f
#define WPOSF_OFF 10240    // f16[4 ks][64 lane][8] = 2048 halves = 1024 f
#define BIASB_OFF 11264    // f32[256]  b_ih + b_hh (gate-major)
#define WSE_OFF   11520    // f32[16][13]  (12 weights + bias per e)
#define SXY_OFF   11728    // f32[16][3]   (Sx, Sy, bse)
#define BPOS_OFF  11776    // f32[12]
#define WCONF_OFF 11788    // f32[384]
#define BCONF_OFF 12172    // f32[6]
#define FLAG_IDX  12180    // int: 1 => inputs fp32, 0 => bf16
#define CONF_BASE (BATCH * 360)

__global__ void detect_kernel(const unsigned short* __restrict__ raw,
                              int* __restrict__ flag_out) {
    __shared__ int sflag[256];
    int local = 0;
    for (int i = threadIdx.x; i < 16384; i += 256) {
        unsigned short u = raw[i];
        if ((u & 0x7F80u) == 0x7F80u) local = 1;
    }
    sflag[threadIdx.x] = local;
    __syncthreads();
    if (threadIdx.x == 0) {
        int f = 0;
        for (int i = 0; i < 256; ++i) f |= sflag[i];
        flag_out[0] = f;
    }
}

__device__ __forceinline__ float ldin(const void* p, int i, int isf32) {
    return isf32 ? ((const float*)p)[i]
                 : (float)((const __hip_bfloat16*)p)[i];
}

__global__ void prep_kernel(const void* __restrict__ W_ih,
                            const void* __restrict__ W_hh,
                            const void* __restrict__ b_ih,
                            const void* __restrict__ b_hh,
                            const void* __restrict__ W_se,
                            const void* __restrict__ b_se,
                            const void* __restrict__ W_pos,
                            const void* __restrict__ b_pos,
                            const void* __restrict__ W_conf,
                            const void* __restrict__ b_conf,
                            float* __restrict__ ws)
{
    const int isf32 = ((const int*)(ws + FLAG_IDX))[0];
    int tid = blockIdx.x * blockDim.x + threadIdx.x;
    int stride = gridDim.x * blockDim.x;
    _Float16* wfh = (_Float16*)ws;

    // Gate-GEMM B fragments: tile tl=(gate*2+ug); B[k][n]: n=lane&31 (unit
    // j=ug*32+n), k = ks*16 + (lane>>5)*8 + jj
    for (int idx = tid; idx < 20480; idx += stride) {
        int tl = idx / 2560, r1 = idx % 2560;
        int ks = r1 / 512, r2 = r1 % 512;
        int lane = r2 >> 3, jj = r2 & 7;
        int gate = tl >> 1, ug = tl & 1;
        int k = ks * 16 + (lane >> 5) * 8 + jj;
        int j = ug * 32 + (lane & 31);
        int row = gate * 64 + j;
        float v = (k < 16) ? ldin(W_ih, row * 16 + k, isf32)
                           : ldin(W_hh, row * 64 + (k - 16), isf32);
        wfh[idx] = (_Float16)v;
    }
    // Wpos B fragments: n=p (col), k = h-unit index (0..63)
    _Float16* wph = (_Float16*)(ws + WPOSF_OFF);
    for (int idx = tid; idx < 2048; idx += stride) {
        int ks = idx / 512, r2 = idx % 512;
        int lane = r2 >> 3, jj = r2 & 7;
        int krel = ks * 16 + (lane >> 5) * 8 + jj;
        int n = lane & 31;
        float v = (n < 12) ? ldin(W_pos, n * 64 + krel, isf32) : 0.0f;
        wph[idx] = (_Float16)v;
    }
    for (int idx = tid; idx < 256; idx += stride)
        ws[BIASB_OFF + idx] = ldin(b_ih, idx, isf32) + ldin(b_hh, idx, isf32);
    for (int idx = tid; idx < 16; idx += stride) {
        for (int p = 0; p < 12; ++p)
            ws[WSE_OFF + idx * 13 + p] = ldin(W_se, idx * 12 + p, isf32);
        ws[WSE_OFF + idx * 13 + 12] = ldin(b_se, idx, isf32);
        float sx = 0.f, sy = 0.f;
        for (int m = 0; m < 6; ++m) {
            sx += ldin(W_se, idx * 12 + 2 * m, isf32);
            sy += ldin(W_se, idx * 12 + 2 * m + 1, isf32);
        }
        ws[SXY_OFF + idx * 3 + 0] = sx;
        ws[SXY_OFF + idx * 3 + 1] = sy;
        ws[SXY_OFF + idx * 3 + 2] = ldin(b_se, idx, isf32);
    }
    for (int idx = tid; idx < 12; idx += stride)
        ws[BPOS_OFF + idx] = ldin(b_pos, idx, isf32);
    for (int idx = tid; idx < 384; idx += stride)
        ws[WCONF_OFF + idx] = ldin(W_conf, idx, isf32);
    for (int idx = tid; idx < 6; idx += stride)
        ws[BCONF_OFF + idx] = ldin(b_conf, idx, isf32);
}

__device__ __forceinline__ float sigmoidf_(float x) {
    return 1.0f / (1.0f + __expf(-x));
}
__device__ __forceinline__ float tanhf_(float x) {
    float ax = fabsf(x);
    float z = __expf(-2.0f * ax);
    float t = (1.0f - z) / (1.0f + z);
    return copysignf(t, x);
}

__device__ __forceinline__ half8 cvt_half8(float4v a, float4v b) {
    half8 r;
#pragma unroll
    for (int i = 0; i < 4; ++i) { r[i] = (_Float16)a[i]; r[4 + i] = (_Float16)b[i]; }
    return r;
}

// block = 256 thr = 4 waves; M = 64 agents/block (2 mtiles of 32).
// wave w: ug = w&1 (unit-group), mt = w>>1 (agent-tile). Wave owns all 4
// gates of its 32 units -> activations fully in-lane, c[16] persistent.
// z (fp32) lives in LDS hTm[m][84pad]: k 0..15 = x, 16..79 = h.
__global__ __launch_bounds__(256, 2) void lstm_kernel(
    const void* __restrict__ traj_rel,
    const void* __restrict__ h0,
    const void* __restrict__ c0,
    const float* __restrict__ ws,
    float* __restrict__ out)
{
    __shared__ float sh[64 * 84 + 12 * 68];
#define HTM 0
#define RELT (64 * 84)

    const int tid = threadIdx.x;
    const int lane = tid & 63;
    const int w = __builtin_amdgcn_readfirstlane(tid >> 6);
    const int ug = w & 1, mt = w >> 1;
    const int col = lane & 31;       // agent-within-mtile (A/C rows) / unit / p
    const int half = lane >> 5;
    const int j = ug * 32 + col;     // this lane's hidden unit
    const int base = blockIdx.x * 64;
    const int isf32 = ((const int*)(ws + FLAG_IDX))[0];

    // ---- per-lane constants ----
    // gate-GEMM B fragments in VGPRs (loaded once, reused 30 steps)
    const float4v* wfg = (const float4v*)ws;
    half8 Bf[4][5];
#pragma unroll
    for (int g = 0; g < 4; ++g)
#pragma unroll
        for (int ks = 0; ks < 5; ++ks)
            Bf[g][ks] = __builtin_bit_cast(half8,
                wfg[((g * 2 + ug) * 5 + ks) * 64 + lane]);
    float bias4[4];
#pragma unroll
    for (int g = 0; g < 4; ++g) bias4[g] = ws[BIASB_OFF + g * 64 + j];

    // rel-mfma constants (waves with ug==0)
    half8 wfp[4];
    float bposv = 0.f;
    if (ug == 0) {
        const float4v* wpg = (const float4v*)(ws + WPOSF_OFF);
#pragma unroll
        for (int ks = 0; ks < 4; ++ks)
            wfp[ks] = __builtin_bit_cast(half8, wpg[ks * 64 + lane]);
        if (col < 12) bposv = ws[BPOS_OFF + col];
    }

    // ---- init: c in regs (C-layout rows), h0 -> hTm, x0 -> hTm ----
    float c[16];
#pragma unroll
    for (int i = 0; i < 16; ++i) {
        int r = (i & 3) + 8 * (i >> 2) + 4 * half;
        c[i] = ldin(c0, (base + mt * 32 + r) * 64 + j, isf32);
    }
    {   // h0: thread t handles (m = t&63, jq = t>>6): 16 j's
        int m = tid & 63, jq = tid >> 6;
#pragma unroll
        for (int q = 0; q < 4; ++q) {
            float4v v;
#pragma unroll
            for (int i = 0; i < 4; ++i)
                v[i] = ldin(h0, (base + m) * 64 + jq * 16 + q * 4 + i, isf32);
            *(float4v*)&sh[HTM + 84 * m + 16 + jq * 16 + q * 4] = v;
        }
        // x0 = lrelu(rx*Sx + ry*Sy + bse); wave w covers e = 4w..4w+3
        float rx = ldin(traj_rel, 2 * (base + lane), isf32);
        float ry = ldin(traj_rel, 2 * (base + lane) + 1, isf32);
        float4v xs;
#pragma unroll
        for (int i = 0; i < 4; ++i) {
            int e = 4 * w + i;
            float x = fmaf(rx, ws[SXY_OFF + e * 3], fmaf(ry, ws[SXY_OFF + e * 3 + 1], ws[SXY_OFF + e * 3 + 2]));
            xs[i] = x > 0.f ? x : 0.01f * x;
        }
        *(float4v*)&sh[HTM + 84 * lane + 4 * w] = xs;
    }
    __syncthreads();

    for (int t = 0; t < TT; ++t) {
        // ---- A: gates = z @ Wcat^T + bias (MFMA) ----
        floatx16 acc[4];
#pragma unroll
        for (int g = 0; g < 4; ++g)
#pragma unroll
            for (int i = 0; i < 16; ++i) acc[g][i] = bias4[g];
#pragma unroll
        for (int ks = 0; ks < 5; ++ks) {
            int za = HTM + 84 * (mt * 32 + col) + ks * 16 + half * 8;
            float4v z0 = *(const float4v*)&sh[za];
            float4v z1 = *(const float4v*)&sh[za + 4];
            half8 af = cvt_half8(z0, z1);
#pragma unroll
            for (int g = 0; g < 4; ++g)
                acc[g] = __builtin_amdgcn_mfma_f32_32x32x16_f16(af, Bf[g][ks], acc[g], 0, 0, 0);
        }
        __syncthreads();  // bar0: all A-reads done before h overwrite

        // ---- B: activations + c update (in-lane), write h -> hTm ----
#pragma unroll
        for (int i = 0; i < 16; ++i) {
            float ii = sigmoidf_(acc[0][i]);
            float ff = sigmoidf_(acc[1][i]);
            float gg = tanhf_(acc[2][i]);
            float oo = sigmoidf_(acc[3][i]);
            float cn = ff * c[i] + ii * gg;
            c[i] = cn;
            float hn = oo * tanhf_(cn);
            int r = (i & 3) + 8 * (i >> 2) + 4 * half;
            sh[HTM + 84 * (mt * 32 + r) + 16 + j] = hn;
        }
        __syncthreads();  // bar1: h complete

        // ---- C: rel = h @ Wpos^T + bpos (MFMA, waves ug==0); pred store ----
        if (ug == 0) {
            floatx16 racc;
#pragma unroll
            for (int i = 0; i < 16; ++i) racc[i] = bposv;
#pragma unroll
            for (int ks = 0; ks < 4; ++ks) {
                int za = HTM + 84 * (mt * 32 + col) + 16 + ks * 16 + half * 8;
                float4v z0 = *(const float4v*)&sh[za];
                float4v z1 = *(const float4v*)&sh[za + 4];
                half8 af = cvt_half8(z0, z1);
                racc = __builtin_amdgcn_mfma_f32_32x32x16_f16(af, wfp[ks], racc, 0, 0, 0);
            }
            if (col < 12) {
#pragma unroll
                for (int q = 0; q < 4; ++q) {
                    float4v v;
#pragma unroll
                    for (int i = 0; i < 4; ++i) v[i] = racc[q * 4 + i];
                    *(float4v*)&sh[RELT + col * 68 + mt * 32 + q * 8 + 4 * half] = v;
                }
#pragma unroll
                for (int i = 0; i < 16; ++i) {
                    int r = (i & 3) + 8 * (i >> 2) + 4 * half;
                    int b = base + mt * 32 + r;
                    out[((size_t)(b * 6 + (col >> 1)) * 30 + t) * 2 + (col & 1)] = racc[i];
                }
            }
        }
        __syncthreads();  // bar2: relT ready

        // ---- D: x = lrelu(rel @ Wse^T + bse); wave w covers e = 4w..4w+3 ----
        {
            float r[12];
#pragma unroll
            for (int p = 0; p < 12; ++p) r[p] = sh[RELT + p * 68 + lane];
            const float* wr = ws + WSE_OFF + (4 * w) * 13;
            float4v xs;
#pragma unroll
            for (int i = 0; i < 4; ++i) {
                float x = wr[i * 13 + 12];
#pragma unroll
                for (int p = 0; p < 12; ++p) x = fmaf(r[p], wr[i * 13 + p], x);
                xs[i] = x > 0.f ? x : 0.01f * x;
            }
            *(float4v*)&sh[HTM + 84 * lane + 4 * w] = xs;
        }
        __syncthreads();  // bar3: x ready for next A
    }

    // ---- conf = softmax(h @ Wconf^T + bconf): wave 0, lane = agent ----
    if (w == 0) {
        int m = lane;
        float l[6];
#pragma unroll
        for (int md = 0; md < 6; ++md) l[md] = ws[BCONF_OFF + md];
        for (int jj = 0; jj < 64; ++jj) {
            float hv = sh[HTM + 84 * m + 16 + jj];
#pragma unroll
            for (int md = 0; md < 6; ++md)
                l[md] = fmaf(hv, ws[WCONF_OFF + md * 64 + jj], l[md]);
        }
        float mx = l[0];
#pragma unroll
        for (int md = 1; md < 6; ++md) mx = fmaxf(mx, l[md]);
        float ex[6], s = 0.f;
#pragma unroll
        for (int md = 0; md < 6; ++md) { ex[md] = __expf(l[md] - mx); s += ex[md]; }
        float inv = 1.0f / s;
#pragma unroll
        for (int md = 0; md < 6; ++md)
            out[CONF_BASE + (size_t)(base + m) * 6 + md] = ex[md] * inv;
    }
}

extern "C" void kernel_launch(void* const* d_in, const int* in_sizes, int n_in,
                              void* d_out, int out_size, void* d_ws, size_t ws_size,
                              hipStream_t stream) {
    const void* traj_rel = d_in[1];
    const void* h0   = d_in[2];
    const void* c0   = d_in[3];
    const void* W_ih = d_in[4];
    const void* W_hh = d_in[5];
    const void* b_ih = d_in[6];
    const void* b_hh = d_in[7];
    const void* W_se = d_in[8];
    const void* b_se = d_in[9];
    const void* W_pos  = d_in[10];
    const void* b_pos  = d_in[11];
    const void* W_conf = d_in[12];
    const void* b_conf = d_in[13];
    float* ws = (float*)d_ws;
    float* out = (float*)d_out;

    detect_kernel<<<1, 256, 0, stream>>>((const unsigned short*)W_hh,
                                         (int*)(ws + FLAG_IDX));
    prep_kernel<<<40, 256, 0, stream>>>(W_ih, W_hh, b_ih, b_hh, W_se, b_se,
                                        W_pos, b_pos, W_conf, b_conf, ws);
    lstm_kernel<<<BATCH / 64, 256, 0, stream>>>(traj_rel, h0, c0, ws, out);
}

// Round 6
// 353.843 us; speedup vs baseline: 2.1853x; 1.2773x over previous
//
#include <hip/hip_runtime.h>
#include <hip/hip_bf16.h>

typedef _Float16 half8 __attribute__((ext_vector_type(8)));
typedef _Float16 half2v __attribute__((ext_vector_type(2)));
typedef float floatx16 __attribute__((ext_vector_type(16)));
typedef float float4v __attribute__((ext_vector_type(4)));

#define BATCH 32768
#define TT 30

// ws offsets (in floats)
#define WFRAG_OFF 0        // f16[8 tiles][5 ks][64 lane][8] = 20480 halves = 10240 f
#define WPOSF_OFF 10240    // f16[4 ks][64 lane][8] = 2048 halves = 1024 f
#define BIASB_OFF 11264    // f32[256]  b_ih + b_hh (gate-major)
#define WSE_OFF   11520    // f32[16][13]  (12 weights + bias per e)
#define SXY_OFF   11728    // f32[16][3]   (Sx, Sy, bse)
#define BPOS_OFF  11776    // f32[12]
#define WCONF_OFF 11788    // f32[384]
#define BCONF_OFF 12172    // f32[6]
#define FLAG_IDX  12180    // int: 1 => inputs fp32, 0 => bf16
#define CONF_BASE (BATCH * 360)

__global__ void detect_kernel(const unsigned short* __restrict__ raw,
                              int* __restrict__ flag_out) {
    __shared__ int sflag[256];
    int local = 0;
    for (int i = threadIdx.x; i < 16384; i += 256) {
        unsigned short u = raw[i];
        if ((u & 0x7F80u) == 0x7F80u) local = 1;
    }
    sflag[threadIdx.x] = local;
    __syncthreads();
    if (threadIdx.x == 0) {
        int f = 0;
        for (int i = 0; i < 256; ++i) f |= sflag[i];
        flag_out[0] = f;
    }
}

__device__ __forceinline__ float ldin(const void* p, int i, int isf32) {
    return isf32 ? ((const float*)p)[i]
                 : (float)((const __hip_bfloat16*)p)[i];
}

__global__ void prep_kernel(const void* __restrict__ W_ih,
                            const void* __restrict__ W_hh,
                            const void* __restrict__ b_ih,
                            const void* __restrict__ b_hh,
                            const void* __restrict__ W_se,
                            const void* __restrict__ b_se,
                            const void* __restrict__ W_pos,
                            const void* __restrict__ b_pos,
                            const void* __restrict__ W_conf,
                            const void* __restrict__ b_conf,
                            float* __restrict__ ws)
{
    const int isf32 = ((const int*)(ws + FLAG_IDX))[0];
    int tid = blockIdx.x * blockDim.x + threadIdx.x;
    int stride = gridDim.x * blockDim.x;
    _Float16* wfh = (_Float16*)ws;

    // Gate-GEMM B fragments: tile tl=(gate*2+ug); B[k][n]: n=lane&31 (unit
    // j=ug*32+n), k = ks*16 + (lane>>5)*8 + jj
    for (int idx = tid; idx < 20480; idx += stride) {
        int tl = idx / 2560, r1 = idx % 2560;
        int ks = r1 / 512, r2 = r1 % 512;
        int lane = r2 >> 3, jj = r2 & 7;
        int gate = tl >> 1, ug = tl & 1;
        int k = ks * 16 + (lane >> 5) * 8 + jj;
        int j = ug * 32 + (lane & 31);
        int row = gate * 64 + j;
        float v = (k < 16) ? ldin(W_ih, row * 16 + k, isf32)
                           : ldin(W_hh, row * 64 + (k - 16), isf32);
        wfh[idx] = (_Float16)v;
    }
    // Wpos B fragments: n=p (col), k = h-unit index (0..63)
    _Float16* wph = (_Float16*)(ws + WPOSF_OFF);
    for (int idx = tid; idx < 2048; idx += stride) {
        int ks = idx / 512, r2 = idx % 512;
        int lane = r2 >> 3, jj = r2 & 7;
        int krel = ks * 16 + (lane >> 5) * 8 + jj;
        int n = lane & 31;
        float v = (n < 12) ? ldin(W_pos, n * 64 + krel, isf32) : 0.0f;
        wph[idx] = (_Float16)v;
    }
    for (int idx = tid; idx < 256; idx += stride)
        ws[BIASB_OFF + idx] = ldin(b_ih, idx, isf32) + ldin(b_hh, idx, isf32);
    for (int idx = tid; idx < 16; idx += stride) {
        for (int p = 0; p < 12; ++p)
            ws[WSE_OFF + idx * 13 + p] = ldin(W_se, idx * 12 + p, isf32);
        ws[WSE_OFF + idx * 13 + 12] = ldin(b_se, idx, isf32);
        float sx = 0.f, sy = 0.f;
        for (int m = 0; m < 6; ++m) {
            sx += ldin(W_se, idx * 12 + 2 * m, isf32);
            sy += ldin(W_se, idx * 12 + 2 * m + 1, isf32);
        }
        ws[SXY_OFF + idx * 3 + 0] = sx;
        ws[SXY_OFF + idx * 3 + 1] = sy;
        ws[SXY_OFF + idx * 3 + 2] = ldin(b_se, idx, isf32);
    }
    for (int idx = tid; idx < 12; idx += stride)
        ws[BPOS_OFF + idx] = ldin(b_pos, idx, isf32);
    for (int idx = tid; idx < 384; idx += stride)
        ws[WCONF_OFF + idx] = ldin(W_conf, idx, isf32);
    for (int idx = tid; idx < 6; idx += stride)
        ws[BCONF_OFF + idx] = ldin(b_conf, idx, isf32);
}

__device__ __forceinline__ float sigmoidf_(float x) {
    return 1.0f / (1.0f + __expf(-x));
}
__device__ __forceinline__ float tanhf_(float x) {
    float ax = fabsf(x);
    float z = __expf(-2.0f * ax);
    float t = (1.0f - z) / (1.0f + z);
    return copysignf(t, x);
}

__device__ __forceinline__ half8 cvt_half8(float4v a, float4v b) {
    half8 r;
#pragma unroll
    for (int i = 0; i < 4; ++i) { r[i] = (_Float16)a[i]; r[4 + i] = (_Float16)b[i]; }
    return r;
}

// block = 256 thr = 4 waves; M = 64 agents/block (2 mtiles of 32).
// wave w: ug = w&1 (unit-group), mt = w>>1 (agent-tile). Wave owns all 4
// gates of its 32 units -> activations fully in-lane, c[16] persistent.
// z (fp32) lives in LDS hTm[m][84pad]: k 0..15 = x, 16..79 = h.
// pred is buffered in LDS (f16, 15 steps) and flushed twice as coalesced
// bursts -- NO global stores inside the barriered loop (vmcnt-drain stall +
// partial-line RMW amplification killed R4).
__global__ __launch_bounds__(256, 2) void lstm_kernel(
    const void* __restrict__ traj_rel,
    const void* __restrict__ h0,
    const void* __restrict__ c0,
    const float* __restrict__ ws,
    float* __restrict__ out)
{
    __shared__ float sh[64 * 84 + 12 * 68 + 5760];
#define HTM 0
#define RELT (64 * 84)
#define PREDB (64 * 84 + 12 * 68)   // 11520 halves = 5760 floats

    const int tid = threadIdx.x;
    const int lane = tid & 63;
    const int w = __builtin_amdgcn_readfirstlane(tid >> 6);
    const int ug = w & 1, mt = w >> 1;
    const int col = lane & 31;       // agent-within-mtile (A/C rows) / unit / p
    const int half = lane >> 5;
    const int j = ug * 32 + col;     // this lane's hidden unit
    const int base = blockIdx.x * 64;
    const int isf32 = ((const int*)(ws + FLAG_IDX))[0];
    _Float16* predh = (_Float16*)&sh[PREDB];

    // ---- per-lane constants ----
    const float4v* wfg = (const float4v*)ws;
    half8 Bf[4][5];
#pragma unroll
    for (int g = 0; g < 4; ++g)
#pragma unroll
        for (int ks = 0; ks < 5; ++ks)
            Bf[g][ks] = __builtin_bit_cast(half8,
                wfg[((g * 2 + ug) * 5 + ks) * 64 + lane]);
    float bias4[4];
#pragma unroll
    for (int g = 0; g < 4; ++g) bias4[g] = ws[BIASB_OFF + g * 64 + j];

    // rel-mfma constants (waves with ug==0)
    half8 wfp[4];
    float bposv = 0.f;
    if (ug == 0) {
        const float4v* wpg = (const float4v*)(ws + WPOSF_OFF);
#pragma unroll
        for (int ks = 0; ks < 4; ++ks)
            wfp[ks] = __builtin_bit_cast(half8, wpg[ks * 64 + lane]);
        if (col < 12) bposv = ws[BPOS_OFF + col];
    }

    // ---- init: c in regs (C-layout rows), h0 -> hTm, x0 -> hTm ----
    float c[16];
#pragma unroll
    for (int i = 0; i < 16; ++i) {
        int r = (i & 3) + 8 * (i >> 2) + 4 * half;
        c[i] = ldin(c0, (base + mt * 32 + r) * 64 + j, isf32);
    }
    {   // h0: thread t handles (m = t&63, jq = t>>6): 16 j's
        int m = tid & 63, jq = tid >> 6;
#pragma unroll
        for (int q = 0; q < 4; ++q) {
            float4v v;
#pragma unroll
            for (int i = 0; i < 4; ++i)
                v[i] = ldin(h0, (base + m) * 64 + jq * 16 + q * 4 + i, isf32);
            *(float4v*)&sh[HTM + 84 * m + 16 + jq * 16 + q * 4] = v;
        }
        // x0 = lrelu(rx*Sx + ry*Sy + bse); wave w covers e = 4w..4w+3
        float rx = ldin(traj_rel, 2 * (base + lane), isf32);
        float ry = ldin(traj_rel, 2 * (base + lane) + 1, isf32);
        float4v xs;
#pragma unroll
        for (int i = 0; i < 4; ++i) {
            int e = 4 * w + i;
            float x = fmaf(rx, ws[SXY_OFF + e * 3], fmaf(ry, ws[SXY_OFF + e * 3 + 1], ws[SXY_OFF + e * 3 + 2]));
            xs[i] = x > 0.f ? x : 0.01f * x;
        }
        *(float4v*)&sh[HTM + 84 * lane + 4 * w] = xs;
    }
    __syncthreads();

    for (int t = 0; t < TT; ++t) {
        // ---- A: gates = z @ Wcat^T + bias (MFMA) ----
        floatx16 acc[4];
#pragma unroll
        for (int g = 0; g < 4; ++g)
#pragma unroll
            for (int i = 0; i < 16; ++i) acc[g][i] = bias4[g];
#pragma unroll
        for (int ks = 0; ks < 5; ++ks) {
            int za = HTM + 84 * (mt * 32 + col) + ks * 16 + half * 8;
            float4v z0 = *(const float4v*)&sh[za];
            float4v z1 = *(const float4v*)&sh[za + 4];
            half8 af = cvt_half8(z0, z1);
#pragma unroll
            for (int g = 0; g < 4; ++g)
                acc[g] = __builtin_amdgcn_mfma_f32_32x32x16_f16(af, Bf[g][ks], acc[g], 0, 0, 0);
        }
        __syncthreads();  // bar0: all A-reads done before h overwrite

        // ---- B: activations + c update (in-lane), write h -> hTm ----
#pragma unroll
        for (int i = 0; i < 16; ++i) {
            float ii = sigmoidf_(acc[0][i]);
            float ff = sigmoidf_(acc[1][i]);
            float gg = tanhf_(acc[2][i]);
            float oo = sigmoidf_(acc[3][i]);
            float cn = ff * c[i] + ii * gg;
            c[i] = cn;
            float hn = oo * tanhf_(cn);
            int r = (i & 3) + 8 * (i >> 2) + 4 * half;
            sh[HTM + 84 * (mt * 32 + r) + 16 + j] = hn;
        }
        __syncthreads();  // bar1: h complete

        // ---- C: rel = h @ Wpos^T + bpos (MFMA, waves ug==0) ----
        if (ug == 0) {
            floatx16 racc;
#pragma unroll
            for (int i = 0; i < 16; ++i) racc[i] = bposv;
#pragma unroll
            for (int ks = 0; ks < 4; ++ks) {
                int za = HTM + 84 * (mt * 32 + col) + 16 + ks * 16 + half * 8;
                float4v z0 = *(const float4v*)&sh[za];
                float4v z1 = *(const float4v*)&sh[za + 4];
                half8 af = cvt_half8(z0, z1);
                racc = __builtin_amdgcn_mfma_f32_32x32x16_f16(af, wfp[ks], racc, 0, 0, 0);
            }
            if (col < 12) {
#pragma unroll
                for (int q = 0; q < 4; ++q) {
                    float4v v;
#pragma unroll
                    for (int i = 0; i < 4; ++i) v[i] = racc[q * 4 + i];
                    *(float4v*)&sh[RELT + col * 68 + mt * 32 + q * 8 + 4 * half] = v;
                }
                // predbuf (f16): pb[a][m][tloc][xy], tloc = t - tb
                int tloc = (t >= 15) ? (t - 15) : t;
#pragma unroll
                for (int i = 0; i < 16; ++i) {
                    int r = (i & 3) + 8 * (i >> 2) + 4 * half;
                    int a = mt * 32 + r;
                    predh[((a * 6 + (col >> 1)) * 15 + tloc) * 2 + (col & 1)] =
                        (_Float16)racc[i];
                }
            }
        }
        __syncthreads();  // bar2: relT + predbuf ready

        // ---- flush predbuf -> out (coalesced), twice per kernel ----
        if (t == 14 || t == 29) {
            const int tb2 = (t == 14) ? 0 : 30;  // global float col offset
            const unsigned int* pbu = (const unsigned int*)predh;
            float* po = out + (size_t)base * 360;
#pragma unroll 1
            for (int q = 0; q < 23; ++q) {
                int d = q * 256 + tid;
                if (d < 5760) {
                    half2v hv = __builtin_bit_cast(half2v, pbu[d]);
                    int row = d / 15;          // a*6+m
                    int rem = (2 * d) % 30;    // tloc*2 + xy
                    float2 o;
                    o.x = (float)hv[0];
                    o.y = (float)hv[1];
                    *(float2*)&po[row * 60 + tb2 + rem] = o;
                }
            }
        }

        // ---- D: x = lrelu(rel @ Wse^T + bse); wave w covers e = 4w..4w+3 ----
        if (t != TT - 1) {
            float r[12];
#pragma unroll
            for (int p = 0; p < 12; ++p) r[p] = sh[RELT + p * 68 + lane];
            const float* wr = ws + WSE_OFF + (4 * w) * 13;
            float4v xs;
#pragma unroll
            for (int i = 0; i < 4; ++i) {
                float x = wr[i * 13 + 12];
#pragma unroll
                for (int p = 0; p < 12; ++p) x = fmaf(r[p], wr[i * 13 + p], x);
                xs[i] = x > 0.f ? x : 0.01f * x;
            }
            *(float4v*)&sh[HTM + 84 * lane + 4 * w] = xs;
        }
        __syncthreads();  // bar3: x ready for next A
    }

    // ---- conf = softmax(h @ Wconf^T + bconf): wave 0, lane = agent ----
    if (w == 0) {
        int m = lane;
        float l[6];
#pragma unroll
        for (int md = 0; md < 6; ++md) l[md] = ws[BCONF_OFF + md];
        for (int jj = 0; jj < 64; ++jj) {
            float hv = sh[HTM + 84 * m + 16 + jj];
#pragma unroll
            for (int md = 0; md < 6; ++md)
                l[md] = fmaf(hv, ws[WCONF_OFF + md * 64 + jj], l[md]);
        }
        float mx = l[0];
#pragma unroll
        for (int md = 1; md < 6; ++md) mx = fmaxf(mx, l[md]);
        float ex[6], s = 0.f;
#pragma unroll
        for (int md = 0; md < 6; ++md) { ex[md] = __expf(l[md] - mx); s += ex[md]; }
        float inv = 1.0f / s;
#pragma unroll
        for (int md = 0; md < 6; ++md)
            out[CONF_BASE + (size_t)(base + m) * 6 + md] = ex[md] * inv;
    }
}

extern "C" void kernel_launch(void* const* d_in, const int* in_sizes, int n_in,
                              void* d_out, int out_size, void* d_ws, size_t ws_size,
                              hipStream_t stream) {
    const void* traj_rel = d_in[1];
    const void* h0   = d_in[2];
    const void* c0   = d_in[3];
    const void* W_ih = d_in[4];
    const void* W_hh = d_in[5];
    const void* b_ih = d_in[6];
    const void* b_hh = d_in[7];
    const void* W_se = d_in[8];
    const void* b_se = d_in[9];
    const void* W_pos  = d_in[10];
    const void* b_pos  = d_in[11];
    const void* W_conf = d_in[12];
    const void* b_conf = d_in[13];
    float* ws = (float*)d_ws;
    float* out = (float*)d_out;

    detect_kernel<<<1, 256, 0, stream>>>((const unsigned short*)W_hh,
                                         (int*)(ws + FLAG_IDX));
    prep_kernel<<<40, 256, 0, stream>>>(W_ih, W_hh, b_ih, b_hh, W_se, b_se,
                                        W_pos, b_pos, W_conf, b_conf, ws);
    lstm_kernel<<<BATCH / 64, 256, 0, stream>>>(traj_rel, h0, c0, ws, out);
}

// Round 7
// 345.857 us; speedup vs baseline: 2.2357x; 1.0231x over previous
//
#include <hip/hip_runtime.h>
#include <hip/hip_bf16.h>

typedef _Float16 half8 __attribute__((ext_vector_type(8)));
typedef _Float16 half4 __attribute__((ext_vector_type(4)));
typedef _Float16 half2v __attribute__((ext_vector_type(2)));
typedef float floatx16 __attribute__((ext_vector_type(16)));
typedef float float4v __attribute__((ext_vector_type(4)));

#define BATCH 32768
#define TT 30

// ws offsets (in floats)
#define WFRAG_OFF 0        // f16[8 tiles][5 ks][64 lane][8] = 20480 halves = 10240 f
#define WPOSF_OFF 10240    // f16[4 ks][64 lane][8] = 2048 halves = 1024 f
#define BIASB_OFF 11264    // f32[256]  b_ih + b_hh (gate-major)
#define WSE_OFF   11520    // f32[16][13]  (12 weights + bias per e)
#define SXY_OFF   11728    // f32[16][3]   (Sx, Sy, bse)
#define BPOS_OFF  11776    // f32[12]
#define WCONF_OFF 11788    // f32[384]
#define BCONF_OFF 12172    // f32[6]
#define FLAG_IDX  12180    // int: 1 => inputs fp32, 0 => bf16
#define CONF_BASE (BATCH * 360)

__global__ void detect_kernel(const unsigned short* __restrict__ raw,
                              int* __restrict__ flag_out) {
    __shared__ int sflag[256];
    int local = 0;
    for (int i = threadIdx.x; i < 16384; i += 256) {
        unsigned short u = raw[i];
        if ((u & 0x7F80u) == 0x7F80u) local = 1;
    }
    sflag[threadIdx.x] = local;
    __syncthreads();
    if (threadIdx.x == 0) {
        int f = 0;
        for (int i = 0; i < 256; ++i) f |= sflag[i];
        flag_out[0] = f;
    }
}

__device__ __forceinline__ float ldin(const void* p, int i, int isf32) {
    return isf32 ? ((const float*)p)[i]
                 : (float)((const __hip_bfloat16*)p)[i];
}

__global__ void prep_kernel(const void* __restrict__ W_ih,
                            const void* __restrict__ W_hh,
                            const void* __restrict__ b_ih,
                            const void* __restrict__ b_hh,
                            const void* __restrict__ W_se,
                            const void* __restrict__ b_se,
                            const void* __restrict__ W_pos,
                            const void* __restrict__ b_pos,
                            const void* __restrict__ W_conf,
                            const void* __restrict__ b_conf,
                            float* __restrict__ ws)
{
    const int isf32 = ((const int*)(ws + FLAG_IDX))[0];
    int tid = blockIdx.x * blockDim.x + threadIdx.x;
    int stride = gridDim.x * blockDim.x;
    _Float16* wfh = (_Float16*)ws;

    // Gate-GEMM B fragments: tile tl=(gate*2+ug); B[k][n]: n=lane&31 (unit
    // j=ug*32+n), k = ks*16 + (lane>>5)*8 + jj
    for (int idx = tid; idx < 20480; idx += stride) {
        int tl = idx / 2560, r1 = idx % 2560;
        int ks = r1 / 512, r2 = r1 % 512;
        int lane = r2 >> 3, jj = r2 & 7;
        int gate = tl >> 1, ug = tl & 1;
        int k = ks * 16 + (lane >> 5) * 8 + jj;
        int j = ug * 32 + (lane & 31);
        int row = gate * 64 + j;
        float v = (k < 16) ? ldin(W_ih, row * 16 + k, isf32)
                           : ldin(W_hh, row * 64 + (k - 16), isf32);
        wfh[idx] = (_Float16)v;
    }
    // Wpos B fragments: n=p (col), k = h-unit index (0..63)
    _Float16* wph = (_Float16*)(ws + WPOSF_OFF);
    for (int idx = tid; idx < 2048; idx += stride) {
        int ks = idx / 512, r2 = idx % 512;
        int lane = r2 >> 3, jj = r2 & 7;
        int krel = ks * 16 + (lane >> 5) * 8 + jj;
        int n = lane & 31;
        float v = (n < 12) ? ldin(W_pos, n * 64 + krel, isf32) : 0.0f;
        wph[idx] = (_Float16)v;
    }
    for (int idx = tid; idx < 256; idx += stride)
        ws[BIASB_OFF + idx] = ldin(b_ih, idx, isf32) + ldin(b_hh, idx, isf32);
    for (int idx = tid; idx < 16; idx += stride) {
        for (int p = 0; p < 12; ++p)
            ws[WSE_OFF + idx * 13 + p] = ldin(W_se, idx * 12 + p, isf32);
        ws[WSE_OFF + idx * 13 + 12] = ldin(b_se, idx, isf32);
        float sx = 0.f, sy = 0.f;
        for (int m = 0; m < 6; ++m) {
            sx += ldin(W_se, idx * 12 + 2 * m, isf32);
            sy += ldin(W_se, idx * 12 + 2 * m + 1, isf32);
        }
        ws[SXY_OFF + idx * 3 + 0] = sx;
        ws[SXY_OFF + idx * 3 + 1] = sy;
        ws[SXY_OFF + idx * 3 + 2] = ldin(b_se, idx, isf32);
    }
    for (int idx = tid; idx < 12; idx += stride)
        ws[BPOS_OFF + idx] = ldin(b_pos, idx, isf32);
    for (int idx = tid; idx < 384; idx += stride)
        ws[WCONF_OFF + idx] = ldin(W_conf, idx, isf32);
    for (int idx = tid; idx < 6; idx += stride)
        ws[BCONF_OFF + idx] = ldin(b_conf, idx, isf32);
}

__device__ __forceinline__ float sigmoidf_(float x) {
    return 1.0f / (1.0f + __expf(-x));
}
__device__ __forceinline__ float tanhf_(float x) {
    // tanh(x) = 2*sigmoid(2x) - 1  (sign-safe, saturation-safe, no abs/copysign)
    float e = __expf(-2.0f * x);
    return fmaf(2.0f, 1.0f / (1.0f + e), -1.0f);
}

__device__ __forceinline__ half8 cvt_half8(float4v a, float4v b) {
    half8 r;
#pragma unroll
    for (int i = 0; i < 4; ++i) { r[i] = (_Float16)a[i]; r[4 + i] = (_Float16)b[i]; }
    return r;
}

// block = 128 thr = 2 waves = the MINIMAL sync domain; M = 32 agents/block.
// wave ug owns hidden units [32ug, 32ug+32); all 4 gates of those units are
// in-lane after MFMA -> activations + persistent c[16] need no cross-lane.
// z (fp32) in LDS zT[agent][84pad]: cols 0..15 = x, 16..79 = h.
// pred buffered f16 in LDS (15 steps), flushed twice, coalesced; NO global
// stores inside the barriered loop. 1024 blocks = 4/CU; 2-wave barriers.
__global__ __launch_bounds__(128, 2) void lstm_kernel(
    const void* __restrict__ traj_rel,
    const void* __restrict__ h0,
    const void* __restrict__ c0,
    const float* __restrict__ ws,
    float* __restrict__ out)
{
    __shared__ float sh[32 * 84 + 12 * 36 + 2880];
#define HTM 0
#define RELT (32 * 84)                 // relT[p][36]
#define PREDB (32 * 84 + 12 * 36)      // 5760 halves: pb[p=m*2+xy][15][32]

    const int tid = threadIdx.x;
    const int lane = tid & 63;
    const int ug = __builtin_amdgcn_readfirstlane(tid >> 6);  // wave id 0/1
    const int col = lane & 31;       // agent (A-rows / C-cols role) / unit / p
    const int half = lane >> 5;
    const int j = ug * 32 + col;     // this lane's hidden unit
    const int base = blockIdx.x * 32;
    const int isf32 = ((const int*)(ws + FLAG_IDX))[0];
    _Float16* predh = (_Float16*)&sh[PREDB];

    // ---- per-lane constants ----
    const float4v* wfg = (const float4v*)ws;
    half8 Bf[4][5];
#pragma unroll
    for (int g = 0; g < 4; ++g)
#pragma unroll
        for (int ks = 0; ks < 5; ++ks)
            Bf[g][ks] = __builtin_bit_cast(half8,
                wfg[((g * 2 + ug) * 5 + ks) * 64 + lane]);
    float bias4[4];
#pragma unroll
    for (int g = 0; g < 4; ++g) bias4[g] = ws[BIASB_OFF + g * 64 + j];

    // rel-mfma constants (wave ug==0)
    half8 wfp[4];
    float bposv = 0.f;
    if (ug == 0) {
        const float4v* wpg = (const float4v*)(ws + WPOSF_OFF);
#pragma unroll
        for (int ks = 0; ks < 4; ++ks)
            wfp[ks] = __builtin_bit_cast(half8, wpg[ks * 64 + lane]);
        if (col < 12) bposv = ws[BPOS_OFF + col];
    }

    // ---- init: c in regs (C-layout rows), h0 -> zT, x0 -> zT ----
    float c[16];
#pragma unroll
    for (int i = 0; i < 16; ++i) {
        int r = (i & 3) + 8 * (i >> 2) + 4 * half;
        c[i] = ldin(c0, (base + r) * 64 + j, isf32);
    }
    {   // h0: thread t -> (m = t&31, jq = t>>5), 16 cols
        int m = tid & 31, jq = tid >> 5;
#pragma unroll
        for (int q = 0; q < 4; ++q) {
            float4v v;
#pragma unroll
            for (int i = 0; i < 4; ++i)
                v[i] = ldin(h0, (base + m) * 64 + jq * 16 + q * 4 + i, isf32);
            *(float4v*)&sh[HTM + 84 * m + 16 + jq * 16 + q * 4] = v;
        }
        // x0 = lrelu(rx*Sx + ry*Sy + bse); thread covers e = 4*jq..+4
        float rx = ldin(traj_rel, 2 * (base + m), isf32);
        float ry = ldin(traj_rel, 2 * (base + m) + 1, isf32);
        float4v xs;
#pragma unroll
        for (int i = 0; i < 4; ++i) {
            int e = 4 * jq + i;
            float x = fmaf(rx, ws[SXY_OFF + e * 3],
                      fmaf(ry, ws[SXY_OFF + e * 3 + 1], ws[SXY_OFF + e * 3 + 2]));
            xs[i] = x > 0.f ? x : 0.01f * x;
        }
        *(float4v*)&sh[HTM + 84 * m + 4 * jq] = xs;
    }
    __syncthreads();

    const int zbase = HTM + 84 * col + half * 8;   // hoisted lane LDS base

    for (int t = 0; t < TT; ++t) {
        // ---- A: gates = z @ Wcat^T + bias (MFMA) ----
        floatx16 acc[4];
#pragma unroll
        for (int g = 0; g < 4; ++g)
#pragma unroll
            for (int i = 0; i < 16; ++i) acc[g][i] = bias4[g];
#pragma unroll
        for (int ks = 0; ks < 5; ++ks) {
            float4v z0 = *(const float4v*)&sh[zbase + ks * 16];
            float4v z1 = *(const float4v*)&sh[zbase + ks * 16 + 4];
            half8 af = cvt_half8(z0, z1);
#pragma unroll
            for (int g = 0; g < 4; ++g)
                acc[g] = __builtin_amdgcn_mfma_f32_32x32x16_f16(af, Bf[g][ks], acc[g], 0, 0, 0);
        }
        __syncthreads();  // bar0: A-reads done before h overwrite

        // ---- B: activations + c update (in-lane), write h -> zT ----
#pragma unroll
        for (int i = 0; i < 16; ++i) {
            float ii = sigmoidf_(acc[0][i]);
            float ff = sigmoidf_(acc[1][i]);
            float gg = tanhf_(acc[2][i]);
            float oo = sigmoidf_(acc[3][i]);
            float cn = ff * c[i] + ii * gg;
            c[i] = cn;
            float hn = oo * tanhf_(cn);
            int r = (i & 3) + 8 * (i >> 2) + 4 * half;
            sh[HTM + 84 * r + 16 + j] = hn;
        }
        __syncthreads();  // bar1: h complete

        // ---- C: rel = h @ Wpos^T + bpos (MFMA, wave 0) ----
        if (ug == 0) {
            floatx16 racc;
#pragma unroll
            for (int i = 0; i < 16; ++i) racc[i] = bposv;
#pragma unroll
            for (int ks = 0; ks < 4; ++ks) {
                float4v z0 = *(const float4v*)&sh[zbase + 16 + ks * 16];
                float4v z1 = *(const float4v*)&sh[zbase + 16 + ks * 16 + 4];
                half8 af = cvt_half8(z0, z1);
                racc = __builtin_amdgcn_mfma_f32_32x32x16_f16(af, wfp[ks], racc, 0, 0, 0);
            }
            if (col < 12) {
                int tl = (t >= 15) ? (t - 15) : t;
#pragma unroll
                for (int q = 0; q < 4; ++q) {
                    float4v v;
                    half4 hv;
#pragma unroll
                    for (int i = 0; i < 4; ++i) {
                        v[i] = racc[q * 4 + i];
                        hv[i] = (_Float16)racc[q * 4 + i];
                    }
                    int a0 = q * 8 + 4 * half;   // 4 consecutive agents
                    *(float4v*)&sh[RELT + col * 36 + a0] = v;
                    *(half4*)&predh[(col * 15 + tl) * 32 + a0] = hv;
                }
            }
        }
        __syncthreads();  // bar2: relT + predbuf ready

        // ---- flush predbuf -> out (coalesced), twice per kernel ----
        if (t == 14 || t == 29) {
            const int tb = (t == 14) ? 0 : 15;   // global t offset (float2)
            float2* po2 = (float2*)out;
#pragma unroll 1
            for (int q = 0; q < 23; ++q) {
                int d = q * 128 + tid;
                if (d < 2880) {
                    int a = d / 90, rem = d % 90;
                    int m = rem / 15, tl = rem % 15;
                    float2 o;
                    o.x = (float)predh[((m * 2 + 0) * 15 + tl) * 32 + a];
                    o.y = (float)predh[((m * 2 + 1) * 15 + tl) * 32 + a];
                    po2[((size_t)(base + a) * 6 + m) * 30 + tb + tl] = o;
                }
            }
        }

        // ---- D: x = lrelu(rel @ Wse^T + bse); lane covers 4 e's ----
        if (t != TT - 1) {
            float r[12];
#pragma unroll
            for (int p = 0; p < 12; ++p) r[p] = sh[RELT + p * 36 + col];
            const int e0 = ug * 8 + half * 4;
            const float* wr = ws + WSE_OFF + e0 * 13;
            float4v xs;
#pragma unroll
            for (int i = 0; i < 4; ++i) {
                float x = wr[i * 13 + 12];
#pragma unroll
                for (int p = 0; p < 12; ++p) x = fmaf(r[p], wr[i * 13 + p], x);
                xs[i] = x > 0.f ? x : 0.01f * x;
            }
            *(float4v*)&sh[HTM + 84 * col + e0] = xs;
        }
        __syncthreads();  // bar3: x ready for next A
    }

    // ---- conf = softmax(h @ Wconf^T + bconf): wave 0, lanes 0..31 ----
    if (ug == 0 && half == 0) {
        int m = col;
        float l[6];
#pragma unroll
        for (int md = 0; md < 6; ++md) l[md] = ws[BCONF_OFF + md];
        for (int jj = 0; jj < 64; ++jj) {
            float hv = sh[HTM + 84 * m + 16 + jj];
#pragma unroll
            for (int md = 0; md < 6; ++md)
                l[md] = fmaf(hv, ws[WCONF_OFF + md * 64 + jj], l[md]);
        }
        float mx = l[0];
#pragma unroll
        for (int md = 1; md < 6; ++md) mx = fmaxf(mx, l[md]);
        float ex[6], s = 0.f;
#pragma unroll
        for (int md = 0; md < 6; ++md) { ex[md] = __expf(l[md] - mx); s += ex[md]; }
        float inv = 1.0f / s;
#pragma unroll
        for (int md = 0; md < 6; ++md)
            out[CONF_BASE + (size_t)(base + m) * 6 + md] = ex[md] * inv;
    }
}

extern "C" void kernel_launch(void* const* d_in, const int* in_sizes, int n_in,
                              void* d_out, int out_size, void* d_ws, size_t ws_size,
                              hipStream_t stream) {
    const void* traj_rel = d_in[1];
    const void* h0   = d_in[2];
    const void* c0   = d_in[3];
    const void* W_ih = d_in[4];
    const void* W_hh = d_in[5];
    const void* b_ih = d_in[6];
    const void* b_hh = d_in[7];
    const void* W_se = d_in[8];
    const void* b_se = d_in[9];
    const void* W_pos  = d_in[10];
    const void* b_pos  = d_in[11];
    const void* W_conf = d_in[12];
    const void* b_conf = d_in[13];
    float* ws = (float*)d_ws;
    float* out = (float*)d_out;

    detect_kernel<<<1, 256, 0, stream>>>((const unsigned short*)W_hh,
                                         (int*)(ws + FLAG_IDX));
    prep_kernel<<<40, 256, 0, stream>>>(W_ih, W_hh, b_ih, b_hh, W_se, b_se,
                                        W_pos, b_pos, W_conf, b_conf, ws);
    lstm_kernel<<<BATCH / 32, 128, 0, stream>>>(traj_rel, h0, c0, ws, out);
}

// Round 8
// 321.715 us; speedup vs baseline: 2.4035x; 1.0750x over previous
//
#include <hip/hip_runtime.h>
#include <hip/hip_bf16.h>

typedef _Float16 half8 __attribute__((ext_vector_type(8)));
typedef _Float16 half4 __attribute__((ext_vector_type(4)));
typedef float floatx16 __attribute__((ext_vector_type(16)));
typedef float float4v __attribute__((ext_vector_type(4)));

#define BATCH 32768
#define TT 30

// ws offsets (in floats)
#define WFRAG_OFF 0        // f16[8 tiles][5 ks][64 lane][8] = 20480 halves
#define WCF_OFF   10240    // f16[2 waves][4 ks][64 lane][8] = 4096 halves (fused C-GEMM: Wpos | M=Wse*Wpos)
#define BIASB_OFF 12288    // f32[256]  b_ih + b_hh (gate-major)
#define SXY_OFF   12544    // f32[16][3]   (Sx, Sy, bse)
#define CBIAS_OFF 12592    // f32[2][32]   (w0: bpos|0, w1: bx=bse+Wse*bpos|0)
#define WCONF_OFF 12656    // f32[384]
#define BCONF_OFF 13040    // f32[6]
#define FLAG_IDX  13056    // int: 1 => inputs fp32, 0 => bf16
#define CONF_BASE (BATCH * 360)

__global__ void detect_kernel(const unsigned short* __restrict__ raw,
                              int* __restrict__ flag_out) {
    __shared__ int sflag[256];
    int local = 0;
    for (int i = threadIdx.x; i < 16384; i += 256) {
        unsigned short u = raw[i];
        if ((u & 0x7F80u) == 0x7F80u) local = 1;
    }
    sflag[threadIdx.x] = local;
    __syncthreads();
    if (threadIdx.x == 0) {
        int f = 0;
        for (int i = 0; i < 256; ++i) f |= sflag[i];
        flag_out[0] = f;
    }
}

__device__ __forceinline__ float ldin(const void* p, int i, int isf32) {
    return isf32 ? ((const float*)p)[i]
                 : (float)((const __hip_bfloat16*)p)[i];
}

__global__ void prep_kernel(const void* __restrict__ W_ih,
                            const void* __restrict__ W_hh,
                            const void* __restrict__ b_ih,
                            const void* __restrict__ b_hh,
                            const void* __restrict__ W_se,
                            const void* __restrict__ b_se,
                            const void* __restrict__ W_pos,
                            const void* __restrict__ b_pos,
                            const void* __restrict__ W_conf,
                            const void* __restrict__ b_conf,
                            float* __restrict__ ws)
{
    const int isf32 = ((const int*)(ws + FLAG_IDX))[0];
    int tid = blockIdx.x * blockDim.x + threadIdx.x;
    int stride = gridDim.x * blockDim.x;
    _Float16* wfh = (_Float16*)ws;

    // Gate-GEMM B fragments: tile tl=(gate*2+ug); B[k][n]: n=lane&31 (unit
    // j=ug*32+n), k = ks*16 + (lane>>5)*8 + jj
    for (int idx = tid; idx < 20480; idx += stride) {
        int tl = idx / 2560, r1 = idx % 2560;
        int ks = r1 / 512, r2 = r1 % 512;
        int lane = r2 >> 3, jj = r2 & 7;
        int gate = tl >> 1, ug = tl & 1;
        int k = ks * 16 + (lane >> 5) * 8 + jj;
        int j = ug * 32 + (lane & 31);
        int row = gate * 64 + j;
        float v = (k < 16) ? ldin(W_ih, row * 16 + k, isf32)
                           : ldin(W_hh, row * 64 + (k - 16), isf32);
        wfh[idx] = (_Float16)v;
    }
    // Fused C-GEMM fragments. wave0 cols: Wpos[n][k] (n<12); wave1 cols:
    // M[n][k] = sum_p Wse[n][p]*Wpos[p][k] (n<16) -- lrelu input is affine
    // in h, so the x-projection folds through rel.
    _Float16* wch = (_Float16*)(ws + WCF_OFF);
    for (int idx = tid; idx < 4096; idx += stride) {
        int w = idx >> 11, r1 = idx & 2047;
        int ks = r1 >> 9, r2 = r1 & 511;
        int lane = r2 >> 3, jj = r2 & 7;
        int n = lane & 31;
        int krel = ks * 16 + (lane >> 5) * 8 + jj;
        float v = 0.f;
        if (w == 0) {
            if (n < 12) v = ldin(W_pos, n * 64 + krel, isf32);
        } else if (n < 16) {
            float s = 0.f;
            for (int p = 0; p < 12; ++p)
                s += ldin(W_se, n * 12 + p, isf32) * ldin(W_pos, p * 64 + krel, isf32);
            v = s;
        }
        wch[idx] = (_Float16)v;
    }
    for (int idx = tid; idx < 256; idx += stride)
        ws[BIASB_OFF + idx] = ldin(b_ih, idx, isf32) + ldin(b_hh, idx, isf32);
    for (int idx = tid; idx < 16; idx += stride) {
        float sx = 0.f, sy = 0.f;
        for (int m = 0; m < 6; ++m) {
            sx += ldin(W_se, idx * 12 + 2 * m, isf32);
            sy += ldin(W_se, idx * 12 + 2 * m + 1, isf32);
        }
        ws[SXY_OFF + idx * 3 + 0] = sx;
        ws[SXY_OFF + idx * 3 + 1] = sy;
        ws[SXY_OFF + idx * 3 + 2] = ldin(b_se, idx, isf32);
    }
    for (int idx = tid; idx < 64; idx += stride) {
        int w = idx >> 5, cc = idx & 31;
        float v = 0.f;
        if (w == 0) {
            if (cc < 12) v = ldin(b_pos, cc, isf32);
        } else if (cc < 16) {
            float s = ldin(b_se, cc, isf32);
            for (int p = 0; p < 12; ++p)
                s += ldin(W_se, cc * 12 + p, isf32) * ldin(b_pos, p, isf32);
            v = s;
        }
        ws[CBIAS_OFF + idx] = v;
    }
    for (int idx = tid; idx < 384; idx += stride)
        ws[WCONF_OFF + idx] = ldin(W_conf, idx, isf32);
    for (int idx = tid; idx < 6; idx += stride)
        ws[BCONF_OFF + idx] = ldin(b_conf, idx, isf32);
}

__device__ __forceinline__ float sigmoidf_(float x) {
    return 1.0f / (1.0f + __expf(-x));
}
__device__ __forceinline__ float tanhf_(float x) {
    float e = __expf(-2.0f * x);
    return fmaf(2.0f, 1.0f / (1.0f + e), -1.0f);
}

__device__ __forceinline__ half8 cvt_half8(float4v a, float4v b) {
    half8 r;
#pragma unroll
    for (int i = 0; i < 4; ++i) { r[i] = (_Float16)a[i]; r[4 + i] = (_Float16)b[i]; }
    return r;
}

// block = 128 thr = 2 waves; M = 32 agents/block. Wave ug owns hidden units
// [32ug, 32ug+32) for the gate GEMM; phase C is the fused (Wpos | Wse*Wpos)
// GEMM: wave0 -> rel/pred cols, wave1 -> x cols (lrelu applied in-register,
// written straight back to zT). 3 barriers/step. pred buffered f16 in LDS
// for ALL 30 steps (row stride 36 halves -> <=2-way banks), single fully
// coalesced float4 flush at the end.
__global__ __launch_bounds__(128, 2) void lstm_kernel(
    const void* __restrict__ traj_rel,
    const void* __restrict__ h0,
    const void* __restrict__ c0,
    const float* __restrict__ ws,
    float* __restrict__ out)
{
    __shared__ float sh[32 * 84 + 6480];
#define HTM 0
#define PREDB (32 * 84)   // 12960 halves: pb[p=m*2+xy][t][36]

    const int tid = threadIdx.x;
    const int lane = tid & 63;
    const int ug = __builtin_amdgcn_readfirstlane(tid >> 6);  // wave id 0/1
    const int col = lane & 31;
    const int half = lane >> 5;
    const int j = ug * 32 + col;
    const int base = blockIdx.x * 32;
    const int isf32 = ((const int*)(ws + FLAG_IDX))[0];
    _Float16* predh = (_Float16*)&sh[PREDB];

    // ---- per-lane constants ----
    const float4v* wfg = (const float4v*)ws;
    half8 Bf[4][5];
#pragma unroll
    for (int g = 0; g < 4; ++g)
#pragma unroll
        for (int ks = 0; ks < 5; ++ks)
            Bf[g][ks] = __builtin_bit_cast(half8,
                wfg[((g * 2 + ug) * 5 + ks) * 64 + lane]);
    float bias4[4];
#pragma unroll
    for (int g = 0; g < 4; ++g) bias4[g] = ws[BIASB_OFF + g * 64 + j];

    // fused C-GEMM fragments + column bias (both waves)
    half8 wfc[4];
    {
        const float4v* wcg = (const float4v*)(ws + WCF_OFF);
#pragma unroll
        for (int ks = 0; ks < 4; ++ks)
            wfc[ks] = __builtin_bit_cast(half8, wcg[(ug * 4 + ks) * 64 + lane]);
    }
    const float cb = ws[CBIAS_OFF + ug * 32 + col];

    // ---- init: c in regs (C-layout rows), h0 -> zT, x0 -> zT ----
    float c[16];
#pragma unroll
    for (int i = 0; i < 16; ++i) {
        int r = (i & 3) + 8 * (i >> 2) + 4 * half;
        c[i] = ldin(c0, (base + r) * 64 + j, isf32);
    }
    {   // h0: thread t -> (m = t&31, jq = t>>5), 16 cols
        int m = tid & 31, jq = tid >> 5;
#pragma unroll
        for (int q = 0; q < 4; ++q) {
            float4v v;
#pragma unroll
            for (int i = 0; i < 4; ++i)
                v[i] = ldin(h0, (base + m) * 64 + jq * 16 + q * 4 + i, isf32);
            *(float4v*)&sh[HTM + 84 * m + 16 + jq * 16 + q * 4] = v;
        }
        // x0 = lrelu(rx*Sx + ry*Sy + bse); thread covers e = 4*jq..+4
        float rx = ldin(traj_rel, 2 * (base + m), isf32);
        float ry = ldin(traj_rel, 2 * (base + m) + 1, isf32);
        float4v xs;
#pragma unroll
        for (int i = 0; i < 4; ++i) {
            int e = 4 * jq + i;
            float x = fmaf(rx, ws[SXY_OFF + e * 3],
                      fmaf(ry, ws[SXY_OFF + e * 3 + 1], ws[SXY_OFF + e * 3 + 2]));
            xs[i] = x > 0.f ? x : 0.01f * x;
        }
        *(float4v*)&sh[HTM + 84 * m + 4 * jq] = xs;
    }
    __syncthreads();

    const int zbase = HTM + 84 * col + half * 8;

    for (int t = 0; t < TT; ++t) {
        // ---- A: gates = z @ Wcat^T + bias (MFMA) ----
        floatx16 acc[4];
#pragma unroll
        for (int g = 0; g < 4; ++g)
#pragma unroll
            for (int i = 0; i < 16; ++i) acc[g][i] = bias4[g];
#pragma unroll
        for (int ks = 0; ks < 5; ++ks) {
            float4v z0 = *(const float4v*)&sh[zbase + ks * 16];
            float4v z1 = *(const float4v*)&sh[zbase + ks * 16 + 4];
            half8 af = cvt_half8(z0, z1);
#pragma unroll
            for (int g = 0; g < 4; ++g)
                acc[g] = __builtin_amdgcn_mfma_f32_32x32x16_f16(af, Bf[g][ks], acc[g], 0, 0, 0);
        }
        __syncthreads();  // bar0: A-reads done before h overwrite

        // ---- B: activations + c update (in-lane), write h -> zT ----
#pragma unroll
        for (int i = 0; i < 16; ++i) {
            float ii = sigmoidf_(acc[0][i]);
            float ff = sigmoidf_(acc[1][i]);
            float gg = tanhf_(acc[2][i]);
            float oo = sigmoidf_(acc[3][i]);
            float cn = ff * c[i] + ii * gg;
            c[i] = cn;
            float hn = oo * tanhf_(cn);
            int r = (i & 3) + 8 * (i >> 2) + 4 * half;
            sh[HTM + 84 * r + 16 + j] = hn;
        }
        __syncthreads();  // bar1: h complete

        // ---- C: fused (rel | x) = h @ [Wpos | M]^T + [bpos | bx] ----
        {
            floatx16 racc;
#pragma unroll
            for (int i = 0; i < 16; ++i) racc[i] = cb;
#pragma unroll
            for (int ks = 0; ks < 4; ++ks) {
                float4v z0 = *(const float4v*)&sh[zbase + 16 + ks * 16];
                float4v z1 = *(const float4v*)&sh[zbase + 16 + ks * 16 + 4];
                half8 af = cvt_half8(z0, z1);
                racc = __builtin_amdgcn_mfma_f32_32x32x16_f16(af, wfc[ks], racc, 0, 0, 0);
            }
            if (ug == 0) {
                // pred store to LDS buffer (f16), row stride 36 halves
                if (col < 12) {
#pragma unroll
                    for (int q = 0; q < 4; ++q) {
                        half4 hv;
#pragma unroll
                        for (int i = 0; i < 4; ++i) hv[i] = (_Float16)racc[q * 4 + i];
                        *(half4*)&predh[(col * 30 + t) * 36 + q * 8 + 4 * half] = hv;
                    }
                }
            } else if (t != TT - 1) {
                // x = lrelu(.) straight back to zT cols 0..15 (e = col)
                if (col < 16) {
#pragma unroll
                    for (int i = 0; i < 16; ++i) {
                        float xv = racc[i];
                        xv = xv > 0.f ? xv : 0.01f * xv;
                        int r = (i & 3) + 8 * (i >> 2) + 4 * half;
                        sh[HTM + 84 * r + col] = xv;
                    }
                }
            }
        }
        __syncthreads();  // bar2: pred/x writes done; next A may read
    }

    // ---- single coalesced flush: predh -> out (float4 per thread-iter) ----
    {
        float4* po4 = (float4*)(out + (size_t)base * 360);
#pragma unroll 1
        for (int q = 0; q < 23; ++q) {
            int idx4 = q * 128 + tid;
            if (idx4 < 2880) {
                int a = idx4 / 90, rem = idx4 % 90;
                int m = rem / 15, tq = rem % 15;
                int t0 = tq * 2;
                float4 o;
                o.x = (float)predh[((2 * m + 0) * 30 + t0) * 36 + a];
                o.y = (float)predh[((2 * m + 1) * 30 + t0) * 36 + a];
                o.z = (float)predh[((2 * m + 0) * 30 + t0 + 1) * 36 + a];
                o.w = (float)predh[((2 * m + 1) * 30 + t0 + 1) * 36 + a];
                po4[idx4] = o;
            }
        }
    }

    // ---- conf = softmax(h @ Wconf^T + bconf): wave 0, lanes 0..31 ----
    if (ug == 0 && half == 0) {
        int m = col;
        float l[6];
#pragma unroll
        for (int md = 0; md < 6; ++md) l[md] = ws[BCONF_OFF + md];
        for (int jj = 0; jj < 64; ++jj) {
            float hv = sh[HTM + 84 * m + 16 + jj];
#pragma unroll
            for (int md = 0; md < 6; ++md)
                l[md] = fmaf(hv, ws[WCONF_OFF + md * 64 + jj], l[md]);
        }
        float mx = l[0];
#pragma unroll
        for (int md = 1; md < 6; ++md) mx = fmaxf(mx, l[md]);
        float ex[6], s = 0.f;
#pragma unroll
        for (int md = 0; md < 6; ++md) { ex[md] = __expf(l[md] - mx); s += ex[md]; }
        float inv = 1.0f / s;
#pragma unroll
        for (int md = 0; md < 6; ++md)
            out[CONF_BASE + (size_t)(base + m) * 6 + md] = ex[md] * inv;
    }
}

extern "C" void kernel_launch(void* const* d_in, const int* in_sizes, int n_in,
                              void* d_out, int out_size, void* d_ws, size_t ws_size,
                              hipStream_t stream) {
    const void* traj_rel = d_in[1];
    const void* h0   = d_in[2];
    const void* c0   = d_in[3];
    const void* W_ih = d_in[4];
    const void* W_hh = d_in[5];
    const void* b_ih = d_in[6];
    const void* b_hh = d_in[7];
    const void* W_se = d_in[8];
    const void* b_se = d_in[9];
    const void* W_pos  = d_in[10];
    const void* b_pos  = d_in[11];
    const void* W_conf = d_in[12];
    const void* b_conf = d_in[13];
    float* ws = (float*)d_ws;
    float* out = (float*)d_out;

    detect_kernel<<<1, 256, 0, stream>>>((const unsigned short*)W_hh,
                                         (int*)(ws + FLAG_IDX));
    prep_kernel<<<40, 256, 0, stream>>>(W_ih, W_hh, b_ih, b_hh, W_se, b_se,
                                        W_pos, b_pos, W_conf, b_conf, ws);
    lstm_kernel<<<BATCH / 32, 128, 0, stream>>>(traj_rel, h0, c0, ws, out);
}